// Round 5
// baseline (188.274 us; speedup 1.0000x reference)
//
#include <hip/hip_runtime.h>

#define HH 96
#define WW 96
#define HW 9216
#define NB 8

typedef __bf16 bf16x8 __attribute__((ext_vector_type(8)));
typedef float  f32x4  __attribute__((ext_vector_type(4)));

union BF8 { uint4 u; bf16x8 v; unsigned short s[8]; };

__device__ __forceinline__ unsigned short f2bf_bits(float f) {
    unsigned u = __float_as_uint(f);
    unsigned r = u + 0x7FFFu + ((u >> 16) & 1u);     // RNE
    return (unsigned short)(r >> 16);
}
__device__ __forceinline__ float bf2f(unsigned short s) {
    return __uint_as_float(((unsigned)s) << 16);
}

// ---------------------------------------------------------------------------
// Kernel 1: x NCHW fp32 -> xt NHWC bf16 with LDS transpose so global stores
// are fully coalesced (2 KB/wave bursts). Blocks < 216 also build
// wTb [tap][co][c] bf16 and owTb [j(32 rows, 18 live)][tap*64+c] bf16.
// ---------------------------------------------------------------------------
__global__ __launch_bounds__(256) void xcvt_prep(const float* __restrict__ x,
                                                 const float* __restrict__ weight,
                                                 const float* __restrict__ off_w,
                                                 unsigned short* __restrict__ xt,
                                                 unsigned short* __restrict__ wTb,
                                                 unsigned short* __restrict__ owTb) {
    __shared__ unsigned short T[64 * 72];   // [px][c], pad 72
    int bid   = blockIdx.x;                 // 1152
    int t     = threadIdx.x;
    int b     = bid & 7;                    // XCD-affine
    int pbase = (bid >> 3) * 64;
    int pl    = t & 63;
    int q     = t >> 6;                     // c-group 0..3

    const float* xp = x + ((size_t)(b * 64 + q * 16)) * HW + pbase + pl;
    unsigned short hb[16];
#pragma unroll
    for (int i = 0; i < 16; ++i) hb[i] = f2bf_bits(xp[(size_t)i * HW]);

    uint4 w0, w1;
    w0.x = hb[0]  | (hb[1]  << 16); w0.y = hb[2]  | (hb[3]  << 16);
    w0.z = hb[4]  | (hb[5]  << 16); w0.w = hb[6]  | (hb[7]  << 16);
    w1.x = hb[8]  | (hb[9]  << 16); w1.y = hb[10] | (hb[11] << 16);
    w1.z = hb[12] | (hb[13] << 16); w1.w = hb[14] | (hb[15] << 16);
    *(uint4*)&T[pl * 72 + q * 16]     = w0;
    *(uint4*)&T[pl * 72 + q * 16 + 8] = w1;
    __syncthreads();

    // coalesced store: thread t owns 16 consecutive shorts of the 8 KB tile
    uint4 a  = *(const uint4*)&T[(t >> 2) * 72 + (t & 3) * 16];
    uint4 b2 = *(const uint4*)&T[(t >> 2) * 72 + (t & 3) * 16 + 8];
    unsigned short* dst = xt + ((size_t)(b * HW + pbase)) * 64 + t * 16;
    *(uint4*)dst       = a;
    *(uint4*)(dst + 8) = b2;

    if (bid < 216) {                        // 216*256 = 36864 + 18432
        int i = bid * 256 + t;
        if (i < 36864) {
            int tap = i >> 12;
            int co  = (i >> 6) & 63;
            int c   = i & 63;
            wTb[i] = f2bf_bits(weight[(co * 64 + c) * 9 + tap]);
        } else {
            int f   = i - 36864;            // f < 18432 = 32*576
            int j   = f / 576;
            int kk  = f - j * 576;
            int tap = kk >> 6;
            int c   = kk & 63;
            owTb[f] = (j < 18) ? f2bf_bits(off_w[(j * 64 + c) * 9 + tap]) : (unsigned short)0;
        }
    }
}

// ---------------------------------------------------------------------------
// Kernel 2 (fused): one 64-lane wave owns a 16-pixel tile.
// Phase A: offset conv via register-direct MFMA (A-frag = zero-masked 3x3
//          patch read; B-frag = owTb row from L1). One LDS transpose.
// Phase B: bilinear sample -> A-frag built IN REGISTERS (lane l&15 = pixel,
//          lane>>4 = 8-channel chunk) -> MFMA vs wTb. No LDS, no barriers.
// ---------------------------------------------------------------------------
__global__ __launch_bounds__(64) void deform_fused(const unsigned short* __restrict__ xt,
                                                   const unsigned short* __restrict__ wTb,
                                                   const unsigned short* __restrict__ owTb,
                                                   const float* __restrict__ bias,
                                                   const float* __restrict__ ob,
                                                   float* __restrict__ off_unused,
                                                   float* __restrict__ out) {
    __shared__ float offs[16 * 20];         // [px_loc][j], pitch 20

    int bid   = blockIdx.x;                 // 4608
    int b     = bid & 7;                    // image per XCD
    int pbase = (bid >> 3) * 16;            // 16-px tile
    int l     = threadIdx.x;
    int ln    = l & 15;                     // m-row = local pixel
    int qd    = l >> 4;                     // k-chunk (8 channels)

    int px = pbase + ln;
    int h  = px / WW;
    int w  = px - h * WW;

    const unsigned short* xb = xt + (size_t)b * HW * 64;

    // ---- phase A: offsets[18] for the tile via MFMA ----
    f32x4 aj0 = {0.f, 0.f, 0.f, 0.f};
    f32x4 aj1 = {0.f, 0.f, 0.f, 0.f};
#pragma unroll
    for (int tap = 0; tap < 9; ++tap) {
        int  r  = tap / 3, s = tap - r * 3;
        int  iy = h - 1 + r, ix = w - 1 + s;
        bool valid = (iy >= 0) & (iy < HH) & (ix >= 0) & (ix < WW);
        int  cy = min(max(iy, 0), HH - 1), cx = min(max(ix, 0), WW - 1);
        const unsigned short* pp = xb + ((size_t)(cy * WW + cx)) * 64 + qd * 8;
        BF8 a0, a1;
        a0.u = *(const uint4*)pp;
        a1.u = *(const uint4*)(pp + 32);
        if (!valid) {
            a0.u = make_uint4(0u, 0u, 0u, 0u);
            a1.u = make_uint4(0u, 0u, 0u, 0u);
        }
        const unsigned short* br0 = owTb + (size_t)ln * 576 + tap * 64 + qd * 8;
        const unsigned short* br1 = owTb + (size_t)(16 + ln) * 576 + tap * 64 + qd * 8;
        aj0 = __builtin_amdgcn_mfma_f32_16x16x32_bf16(a0.v, *(const bf16x8*)br0,        aj0, 0, 0, 0);
        aj0 = __builtin_amdgcn_mfma_f32_16x16x32_bf16(a1.v, *(const bf16x8*)(br0 + 32), aj0, 0, 0, 0);
        aj1 = __builtin_amdgcn_mfma_f32_16x16x32_bf16(a0.v, *(const bf16x8*)br1,        aj1, 0, 0, 0);
        aj1 = __builtin_amdgcn_mfma_f32_16x16x32_bf16(a1.v, *(const bf16x8*)(br1 + 32), aj1, 0, 0, 0);
    }
    // transpose D (col=j, row=px) -> offs[px][j]
    {
        float obj = ob[ln];
#pragma unroll
        for (int rg = 0; rg < 4; ++rg) offs[(qd * 4 + rg) * 20 + ln] = aj0[rg] + obj;
        if (ln < 2) {
            float obj1 = ob[16 + ln];
#pragma unroll
            for (int rg = 0; rg < 4; ++rg) offs[(qd * 4 + rg) * 20 + 16 + ln] = aj1[rg] + obj1;
        }
    }
    __syncthreads();

    float offy[9], offx[9];
#pragma unroll
    for (int k = 0; k < 9; ++k) {
        offy[k] = offs[ln * 20 + 2 * k];
        offx[k] = offs[ln * 20 + 2 * k + 1];
    }

    // ---- phase B: sample + main MFMA, all in registers ----
    f32x4 acc[4] = {{0.f,0.f,0.f,0.f},{0.f,0.f,0.f,0.f},{0.f,0.f,0.f,0.f},{0.f,0.f,0.f,0.f}};

#pragma unroll
    for (int tap = 0; tap < 9; ++tap) {
        int   r = tap / 3, s = tap - r * 3;
        float sy = (float)(h + r) + offy[tap];
        float sx = (float)(w + s) + offx[tap];
        float fy = floorf(sy), fx = floorf(sx);
        int   y0 = (int)fy, x0 = (int)fx;
        int   y1 = y0 + 1, x1 = x0 + 1;
        float wy1 = sy - fy, wx1 = sx - fx;
        float wy0 = 1.f - wy1, wx0 = 1.f - wx1;

        float m00 = (y0 >= 0 && y0 < HH && x0 >= 0 && x0 < WW) ? 1.f : 0.f;
        float m01 = (y0 >= 0 && y0 < HH && x1 >= 0 && x1 < WW) ? 1.f : 0.f;
        float m10 = (y1 >= 0 && y1 < HH && x0 >= 0 && x0 < WW) ? 1.f : 0.f;
        float m11 = (y1 >= 0 && y1 < HH && x1 >= 0 && x1 < WW) ? 1.f : 0.f;

        int cy0 = min(max(y0, 0), HH - 1), cy1 = min(max(y1, 0), HH - 1);
        int cx0 = min(max(x0, 0), WW - 1), cx1 = min(max(x1, 0), WW - 1);
        float w00 = wy0 * wx0 * m00, w01 = wy0 * wx1 * m01;
        float w10 = wy1 * wx0 * m10, w11 = wy1 * wx1 * m11;

        const unsigned short* p00 = xb + ((size_t)(cy0 * WW + cx0)) * 64 + qd * 8;
        const unsigned short* p01 = xb + ((size_t)(cy0 * WW + cx1)) * 64 + qd * 8;
        const unsigned short* p10 = xb + ((size_t)(cy1 * WW + cx0)) * 64 + qd * 8;
        const unsigned short* p11 = xb + ((size_t)(cy1 * WW + cx1)) * 64 + qd * 8;

        BF8 c00a, c00b, c01a, c01b, c10a, c10b, c11a, c11b;
        c00a.u = *(const uint4*)p00;  c00b.u = *(const uint4*)(p00 + 32);
        c01a.u = *(const uint4*)p01;  c01b.u = *(const uint4*)(p01 + 32);
        c10a.u = *(const uint4*)p10;  c10b.u = *(const uint4*)(p10 + 32);
        c11a.u = *(const uint4*)p11;  c11b.u = *(const uint4*)(p11 + 32);

        BF8 A0, A1;                   // A-frag: pixel ln, channels qd*8..(+32)
#pragma unroll
        for (int i = 0; i < 8; ++i) {
            float v0 = w00 * bf2f(c00a.s[i]) + w01 * bf2f(c01a.s[i])
                     + w10 * bf2f(c10a.s[i]) + w11 * bf2f(c11a.s[i]);
            float v1 = w00 * bf2f(c00b.s[i]) + w01 * bf2f(c01b.s[i])
                     + w10 * bf2f(c10b.s[i]) + w11 * bf2f(c11b.s[i]);
            A0.s[i] = f2bf_bits(v0);
            A1.s[i] = f2bf_bits(v1);
        }

#pragma unroll
        for (int ct = 0; ct < 4; ++ct) {
            const unsigned short* wrow = wTb + (size_t)tap * 4096 + (ct * 16 + ln) * 64 + qd * 8;
            acc[ct] = __builtin_amdgcn_mfma_f32_16x16x32_bf16(A0.v, *(const bf16x8*)wrow,        acc[ct], 0, 0, 0);
            acc[ct] = __builtin_amdgcn_mfma_f32_16x16x32_bf16(A1.v, *(const bf16x8*)(wrow + 32), acc[ct], 0, 0, 0);
        }
    }

    // ---- epilogue: D col=co (ln), rows px = qd*4+reg -> float4 stores ----
#pragma unroll
    for (int ct = 0; ct < 4; ++ct) {
        int   co = ct * 16 + ln;
        float bv = bias[co];
        float4 st;
        st.x = acc[ct][0] + bv; st.y = acc[ct][1] + bv;
        st.z = acc[ct][2] + bv; st.w = acc[ct][3] + bv;
        *(float4*)(out + ((size_t)(b * 64 + co)) * HW + pbase + qd * 4) = st;
    }
}

// ---------------------------------------------------------------------------
extern "C" void kernel_launch(void* const* d_in, const int* in_sizes, int n_in,
                              void* d_out, int out_size, void* d_ws, size_t ws_size,
                              hipStream_t stream) {
    const float* x      = (const float*)d_in[0];   // 8*64*96*96
    const float* weight = (const float*)d_in[1];   // 64*64*3*3
    const float* bias   = (const float*)d_in[2];   // 64
    const float* off_w  = (const float*)d_in[3];   // 18*64*3*3
    const float* off_b  = (const float*)d_in[4];   // 18
    float* out = (float*)d_out;

    unsigned short* xt   = (unsigned short*)d_ws;  // 4,718,592 bf16
    unsigned short* wTb  = xt + 4718592;           // 36,864 bf16
    unsigned short* owTb = wTb + 36864;            // 18,432 bf16

    hipLaunchKernelGGL(xcvt_prep,    dim3(1152), dim3(256), 0, stream,
                       x, weight, off_w, xt, wTb, owTb);
    hipLaunchKernelGGL(deform_fused, dim3(4608), dim3(64), 0, stream,
                       xt, wTb, owTb, bias, off_b, (float*)nullptr, out);
}

// Round 6
// 187.420 us; speedup vs baseline: 1.0046x; 1.0046x over previous
//
#include <hip/hip_runtime.h>

#define HH 96
#define WW 96
#define HW 9216
#define NB 8

typedef __bf16 bf16x8 __attribute__((ext_vector_type(8)));
typedef float  f32x4  __attribute__((ext_vector_type(4)));

union BF8 { uint4 u; bf16x8 v; unsigned short s[8]; };

__device__ __forceinline__ unsigned short f2bf_bits(float f) {
    unsigned u = __float_as_uint(f);
    unsigned r = u + 0x7FFFu + ((u >> 16) & 1u);     // RNE
    return (unsigned short)(r >> 16);
}
__device__ __forceinline__ float bf2f(unsigned short s) {
    return __uint_as_float(((unsigned)s) << 16);
}

// ---------------------------------------------------------------------------
// Kernel 1: x NCHW fp32 -> xt NHWC bf16 (unchanged from R5 — isolate variable).
// Blocks < 216 also build wTb [tap][co][c] bf16 and owTb [j(32)][tap*64+c].
// ---------------------------------------------------------------------------
__global__ __launch_bounds__(256) void xcvt_prep(const float* __restrict__ x,
                                                 const float* __restrict__ weight,
                                                 const float* __restrict__ off_w,
                                                 unsigned short* __restrict__ xt,
                                                 unsigned short* __restrict__ wTb,
                                                 unsigned short* __restrict__ owTb) {
    __shared__ unsigned short T[64 * 72];   // [px][c], pad 72
    int bid   = blockIdx.x;                 // 1152
    int t     = threadIdx.x;
    int b     = bid & 7;                    // XCD-affine
    int pbase = (bid >> 3) * 64;
    int pl    = t & 63;
    int q     = t >> 6;                     // c-group 0..3

    const float* xp = x + ((size_t)(b * 64 + q * 16)) * HW + pbase + pl;
    unsigned short hb[16];
#pragma unroll
    for (int i = 0; i < 16; ++i) hb[i] = f2bf_bits(xp[(size_t)i * HW]);

    uint4 w0, w1;
    w0.x = hb[0]  | (hb[1]  << 16); w0.y = hb[2]  | (hb[3]  << 16);
    w0.z = hb[4]  | (hb[5]  << 16); w0.w = hb[6]  | (hb[7]  << 16);
    w1.x = hb[8]  | (hb[9]  << 16); w1.y = hb[10] | (hb[11] << 16);
    w1.z = hb[12] | (hb[13] << 16); w1.w = hb[14] | (hb[15] << 16);
    *(uint4*)&T[pl * 72 + q * 16]     = w0;
    *(uint4*)&T[pl * 72 + q * 16 + 8] = w1;
    __syncthreads();

    uint4 a  = *(const uint4*)&T[(t >> 2) * 72 + (t & 3) * 16];
    uint4 b2 = *(const uint4*)&T[(t >> 2) * 72 + (t & 3) * 16 + 8];
    unsigned short* dst = xt + ((size_t)(b * HW + pbase)) * 64 + t * 16;
    *(uint4*)dst       = a;
    *(uint4*)(dst + 8) = b2;

    if (bid < 216) {                        // 216*256 = 36864 + 18432
        int i = bid * 256 + t;
        if (i < 36864) {
            int tap = i >> 12;
            int co  = (i >> 6) & 63;
            int c   = i & 63;
            wTb[i] = f2bf_bits(weight[(co * 64 + c) * 9 + tap]);
        } else {
            int f   = i - 36864;            // f < 18432 = 32*576
            int j   = f / 576;
            int kk  = f - j * 576;
            int tap = kk >> 6;
            int c   = kk & 63;
            owTb[f] = (j < 18) ? f2bf_bits(off_w[(j * 64 + c) * 9 + tap]) : (unsigned short)0;
        }
    }
}

// ---------------------------------------------------------------------------
// Kernel 2 (fused, 256-thread blocks): 4 independent waves per block, each
// wave owns a 16-pixel tile (register-direct MFMA A-fragments, no staging
// LDS). 256-thread blocks lift residency 8 -> ~28 waves/CU (the R5 64-thread
// version was capped at 8 waves/CU and latency-starved).
// ---------------------------------------------------------------------------
__global__ __launch_bounds__(256) void deform_fused(const unsigned short* __restrict__ xt,
                                                    const unsigned short* __restrict__ wTb,
                                                    const unsigned short* __restrict__ owTb,
                                                    const float* __restrict__ bias,
                                                    const float* __restrict__ ob,
                                                    float* __restrict__ out) {
    __shared__ float offs[4 * 16 * 20];     // per-wave [16 px][18+pad j]

    int bid   = blockIdx.x;                 // 1152
    int t     = threadIdx.x;
    int b     = bid & 7;                    // image per XCD
    int wv    = t >> 6;                     // wave 0..3
    int l     = t & 63;
    int ln    = l & 15;                     // m-row = local pixel
    int qd    = l >> 4;                     // k-chunk (8 channels)
    int pbase = (bid >> 3) * 64 + wv * 16;  // this wave's 16-px tile

    int px = pbase + ln;
    int h  = px / WW;
    int w  = px - h * WW;

    const unsigned short* xb = xt + (size_t)b * HW * 64;
    float* offw = &offs[wv * 320];

    // ---- phase A: offsets[18] for the tile via MFMA ----
    f32x4 aj0 = {0.f, 0.f, 0.f, 0.f};
    f32x4 aj1 = {0.f, 0.f, 0.f, 0.f};
#pragma unroll
    for (int tap = 0; tap < 9; ++tap) {
        int  r  = tap / 3, s = tap - r * 3;
        int  iy = h - 1 + r, ix = w - 1 + s;
        bool valid = (iy >= 0) & (iy < HH) & (ix >= 0) & (ix < WW);
        int  cy = min(max(iy, 0), HH - 1), cx = min(max(ix, 0), WW - 1);
        const unsigned short* pp = xb + ((size_t)(cy * WW + cx)) * 64 + qd * 8;
        BF8 a0, a1;
        a0.u = *(const uint4*)pp;
        a1.u = *(const uint4*)(pp + 32);
        if (!valid) {
            a0.u = make_uint4(0u, 0u, 0u, 0u);
            a1.u = make_uint4(0u, 0u, 0u, 0u);
        }
        const unsigned short* br0 = owTb + (size_t)ln * 576 + tap * 64 + qd * 8;
        const unsigned short* br1 = owTb + (size_t)(16 + ln) * 576 + tap * 64 + qd * 8;
        aj0 = __builtin_amdgcn_mfma_f32_16x16x32_bf16(a0.v, *(const bf16x8*)br0,        aj0, 0, 0, 0);
        aj0 = __builtin_amdgcn_mfma_f32_16x16x32_bf16(a1.v, *(const bf16x8*)(br0 + 32), aj0, 0, 0, 0);
        aj1 = __builtin_amdgcn_mfma_f32_16x16x32_bf16(a0.v, *(const bf16x8*)br1,        aj1, 0, 0, 0);
        aj1 = __builtin_amdgcn_mfma_f32_16x16x32_bf16(a1.v, *(const bf16x8*)(br1 + 32), aj1, 0, 0, 0);
    }
    // transpose D (col=j, row=px) -> offs[px][j]
    {
        float obj = ob[ln];
#pragma unroll
        for (int rg = 0; rg < 4; ++rg) offw[(qd * 4 + rg) * 20 + ln] = aj0[rg] + obj;
        if (ln < 2) {
            float obj1 = ob[16 + ln];
#pragma unroll
            for (int rg = 0; rg < 4; ++rg) offw[(qd * 4 + rg) * 20 + 16 + ln] = aj1[rg] + obj1;
        }
    }
    __syncthreads();

    float offy[9], offx[9];
#pragma unroll
    for (int k = 0; k < 9; ++k) {
        offy[k] = offw[ln * 20 + 2 * k];
        offx[k] = offw[ln * 20 + 2 * k + 1];
    }

    // ---- phase B: sample + main MFMA, all in registers ----
    f32x4 acc[4] = {{0.f,0.f,0.f,0.f},{0.f,0.f,0.f,0.f},{0.f,0.f,0.f,0.f},{0.f,0.f,0.f,0.f}};

#pragma unroll
    for (int tap = 0; tap < 9; ++tap) {
        int   r = tap / 3, s = tap - r * 3;
        float sy = (float)(h + r) + offy[tap];
        float sx = (float)(w + s) + offx[tap];
        float fy = floorf(sy), fx = floorf(sx);
        int   y0 = (int)fy, x0 = (int)fx;
        int   y1 = y0 + 1, x1 = x0 + 1;
        float wy1 = sy - fy, wx1 = sx - fx;
        float wy0 = 1.f - wy1, wx0 = 1.f - wx1;

        float m00 = (y0 >= 0 && y0 < HH && x0 >= 0 && x0 < WW) ? 1.f : 0.f;
        float m01 = (y0 >= 0 && y0 < HH && x1 >= 0 && x1 < WW) ? 1.f : 0.f;
        float m10 = (y1 >= 0 && y1 < HH && x0 >= 0 && x0 < WW) ? 1.f : 0.f;
        float m11 = (y1 >= 0 && y1 < HH && x1 >= 0 && x1 < WW) ? 1.f : 0.f;

        int cy0 = min(max(y0, 0), HH - 1), cy1 = min(max(y1, 0), HH - 1);
        int cx0 = min(max(x0, 0), WW - 1), cx1 = min(max(x1, 0), WW - 1);
        float w00 = wy0 * wx0 * m00, w01 = wy0 * wx1 * m01;
        float w10 = wy1 * wx0 * m10, w11 = wy1 * wx1 * m11;

        const unsigned short* p00 = xb + ((size_t)(cy0 * WW + cx0)) * 64 + qd * 8;
        const unsigned short* p01 = xb + ((size_t)(cy0 * WW + cx1)) * 64 + qd * 8;
        const unsigned short* p10 = xb + ((size_t)(cy1 * WW + cx0)) * 64 + qd * 8;
        const unsigned short* p11 = xb + ((size_t)(cy1 * WW + cx1)) * 64 + qd * 8;

        BF8 c00a, c00b, c01a, c01b, c10a, c10b, c11a, c11b;
        c00a.u = *(const uint4*)p00;  c00b.u = *(const uint4*)(p00 + 32);
        c01a.u = *(const uint4*)p01;  c01b.u = *(const uint4*)(p01 + 32);
        c10a.u = *(const uint4*)p10;  c10b.u = *(const uint4*)(p10 + 32);
        c11a.u = *(const uint4*)p11;  c11b.u = *(const uint4*)(p11 + 32);

        BF8 A0, A1;                   // A-frag: pixel ln, channels qd*8..(+32)
#pragma unroll
        for (int i = 0; i < 8; ++i) {
            float v0 = w00 * bf2f(c00a.s[i]) + w01 * bf2f(c01a.s[i])
                     + w10 * bf2f(c10a.s[i]) + w11 * bf2f(c11a.s[i]);
            float v1 = w00 * bf2f(c00b.s[i]) + w01 * bf2f(c01b.s[i])
                     + w10 * bf2f(c10b.s[i]) + w11 * bf2f(c11b.s[i]);
            A0.s[i] = f2bf_bits(v0);
            A1.s[i] = f2bf_bits(v1);
        }

#pragma unroll
        for (int ct = 0; ct < 4; ++ct) {
            const unsigned short* wrow = wTb + (size_t)tap * 4096 + (ct * 16 + ln) * 64 + qd * 8;
            acc[ct] = __builtin_amdgcn_mfma_f32_16x16x32_bf16(A0.v, *(const bf16x8*)wrow,        acc[ct], 0, 0, 0);
            acc[ct] = __builtin_amdgcn_mfma_f32_16x16x32_bf16(A1.v, *(const bf16x8*)(wrow + 32), acc[ct], 0, 0, 0);
        }
    }

    // ---- epilogue: D col=co (ln), rows px = qd*4+reg -> float4 stores ----
#pragma unroll
    for (int ct = 0; ct < 4; ++ct) {
        int   co = ct * 16 + ln;
        float bv = bias[co];
        float4 st;
        st.x = acc[ct][0] + bv; st.y = acc[ct][1] + bv;
        st.z = acc[ct][2] + bv; st.w = acc[ct][3] + bv;
        *(float4*)(out + ((size_t)(b * 64 + co)) * HW + pbase + qd * 4) = st;
    }
}

// ---------------------------------------------------------------------------
extern "C" void kernel_launch(void* const* d_in, const int* in_sizes, int n_in,
                              void* d_out, int out_size, void* d_ws, size_t ws_size,
                              hipStream_t stream) {
    const float* x      = (const float*)d_in[0];   // 8*64*96*96
    const float* weight = (const float*)d_in[1];   // 64*64*3*3
    const float* bias   = (const float*)d_in[2];   // 64
    const float* off_w  = (const float*)d_in[3];   // 18*64*3*3
    const float* off_b  = (const float*)d_in[4];   // 18
    float* out = (float*)d_out;

    unsigned short* xt   = (unsigned short*)d_ws;  // 4,718,592 bf16
    unsigned short* wTb  = xt + 4718592;           // 36,864 bf16
    unsigned short* owTb = wTb + 36864;            // 18,432 bf16

    hipLaunchKernelGGL(xcvt_prep,    dim3(1152), dim3(256), 0, stream,
                       x, weight, off_w, xt, wTb, owTb);
    hipLaunchKernelGGL(deform_fused, dim3(1152), dim3(256), 0, stream,
                       xt, wTb, owTb, bias, off_b, out);
}